// Round 5
// baseline (245.574 us; speedup 1.0000x reference)
//
#include <hip/hip_runtime.h>
#include <math.h>

#define N_NODES 50000
#define N_EDGES 800000
#define HID 128
#define CAP 64                 // max in-degree; Poisson(16) -> P(>64) ~ 1e-18
#define GQ_GRID ((N_NODES + 31) / 32)   // 1563 (32-row qkv blocks)
#define GO_GRID ((N_NODES + 63) / 64)   // 782  (64-row out blocks)

typedef __bf16 bf16_t;
typedef bf16_t bf16x8 __attribute__((ext_vector_type(8)));
typedef float  f32x4  __attribute__((ext_vector_type(4)));

__device__ __forceinline__ ushort f2b(float x) {
    union { bf16_t b; ushort u; } c;
    c.b = (bf16_t)x;           // fptrunc f32->bf16, RNE
    return c.u;
}

// ---------------------------------------------------------------------------
// prep: edge scatter (latency-bound) + 4 weight-matrix f32->bf16 cvt (tiny).
// cnt zeroed by a prior hipMemsetAsync. h is NOT converted here — the QKV
// GEMM consumes f32 h directly with in-register cvt.
__global__ __launch_bounds__(256) void prep(
    const float* __restrict__ Wq, const float* __restrict__ Wk,
    const float* __restrict__ Wv, const float* __restrict__ Wo,
    ushort* __restrict__ wq, ushort* __restrict__ wk,
    ushort* __restrict__ wv, ushort* __restrict__ wo,
    const int* __restrict__ rows, const int* __restrict__ cols,
    int* __restrict__ cnt, ushort* __restrict__ slots)
{
    const int t = blockIdx.x * 256 + threadIdx.x;

    if (t < 4 * 4096) {                       // 4 mats x 4096 float4
        int w = t >> 12, i = t & 4095;
        const float* src = (w == 0) ? Wq : (w == 1) ? Wk : (w == 2) ? Wv : Wo;
        ushort*      dst = (w == 0) ? wq : (w == 1) ? wk : (w == 2) ? wv : wo;
        float4 f = ((const float4*)src)[i];
        ushort4 o;
        o.x = f2b(f.x); o.y = f2b(f.y); o.z = f2b(f.z); o.w = f2b(f.w);
        ((ushort4*)dst)[i] = o;
    }
    if (t < N_EDGES) {
        int r = rows[t];
        int p = atomicAdd(&cnt[r], 1);
        if (p < CAP) slots[r * CAP + p] = (ushort)cols[t];
    }
}

// ---------------------------------------------------------------------------
// Fused QKV projection, MFMA 16x16x32 bf16. Block = 4 waves x 32 rows.
// Wave w owns cols [w*32, w*32+32) (2 n-tiles) for 2 row-strips; A read once
// from f32 h (in-register cvt) and reused for Q, K, V.
// Pack layout (matches attn): c = w*32+16t+m -> p = 16w+8t+(m&7), half = m>>3.
//   qp[row*64+p] uint  : halves = bf16 q_c (m<8) | q_{c+8} (m>=8), *0.25
//   kv[row*64+p] uint2 : x = k pair, y = v pair.
// Each 64B kv line (8 uint2, fixed row, one (w,t)) is FULLY written by one
// wave (K covers x-words, V covers y-words) -> no partial-line allocate, no
// cross-XCD ping-pong (round-4's hidden cost).
__global__ __launch_bounds__(256) void gemm_qkv(
    const float* __restrict__ h,
    const ushort* __restrict__ wqm, const ushort* __restrict__ wkm,
    const ushort* __restrict__ wvm,
    const float* __restrict__ bq, const float* __restrict__ bk,
    const float* __restrict__ bv,
    uint* __restrict__ qp, uint2* __restrict__ kv)
{
    const int lane = threadIdx.x & 63;
    const int wid  = threadIdx.x >> 6;
    const int mrow = lane & 15;
    const int quad = lane >> 4;
    const int rb   = blockIdx.x * 32;

    // A fragments: 2 strips x 4 k-chunks, f32 -> bf16 in-register
    bf16x8 a[2][4];
#pragma unroll
    for (int s = 0; s < 2; ++s) {
        if (rb + s * 16 >= N_NODES) break;
        const float* src = h + (size_t)(rb + s * 16 + mrow) * HID + quad * 8;
#pragma unroll
        for (int kc = 0; kc < 4; ++kc) {
            float4 f0 = *(const float4*)(src + kc * 32);
            float4 f1 = *(const float4*)(src + kc * 32 + 4);
            bf16x8 tb;
            tb[0] = (bf16_t)f0.x; tb[1] = (bf16_t)f0.y;
            tb[2] = (bf16_t)f0.z; tb[3] = (bf16_t)f0.w;
            tb[4] = (bf16_t)f1.x; tb[5] = (bf16_t)f1.y;
            tb[6] = (bf16_t)f1.z; tb[7] = (bf16_t)f1.w;
            a[s][kc] = tb;
        }
    }

    const int c0   = wid * 32 + mrow;      // t=0 column
    const int c1   = c0 + 16;              // t=1 column
    const int p0   = 16 * wid + (mrow & 7);
    const int half = mrow >> 3;

    bf16x8 bfr[2][4];
    f32x4  acc[2][2];

#define LOAD_B(W)                                                          \
    _Pragma("unroll")                                                      \
    for (int kc = 0; kc < 4; ++kc) {                                       \
        bfr[0][kc] = *(const bf16x8*)((W) + c0 * HID + kc * 32 + quad * 8);\
        bfr[1][kc] = *(const bf16x8*)((W) + c1 * HID + kc * 32 + quad * 8);\
    }
#define RUN_MFMA(dst)                                                      \
    _Pragma("unroll")                                                      \
    for (int s = 0; s < 2; ++s) {                                          \
        dst[s][0] = (f32x4){0.f, 0.f, 0.f, 0.f};                           \
        dst[s][1] = (f32x4){0.f, 0.f, 0.f, 0.f};                           \
        if (rb + s * 16 >= N_NODES) continue;                              \
        _Pragma("unroll")                                                  \
        for (int kc = 0; kc < 4; ++kc) {                                   \
            dst[s][0] = __builtin_amdgcn_mfma_f32_16x16x32_bf16(           \
                a[s][kc], bfr[0][kc], dst[s][0], 0, 0, 0);                 \
            dst[s][1] = __builtin_amdgcn_mfma_f32_16x16x32_bf16(           \
                a[s][kc], bfr[1][kc], dst[s][1], 0, 0, 0);                 \
        }                                                                  \
    }

    // ---- Q ----
    LOAD_B(wqm);
    RUN_MFMA(acc);
    {
        const float b0 = bq[c0], b1 = bq[c1];
        ushort* qps = (ushort*)qp;
#pragma unroll
        for (int s = 0; s < 2; ++s) {
            if (rb + s * 16 >= N_NODES) break;
#pragma unroll
            for (int r = 0; r < 4; ++r) {
                const size_t orow = rb + s * 16 + quad * 4 + r;
                qps[((orow * 64 + p0) << 1) + half]     = f2b((acc[s][0][r] + b0) * 0.25f);
                qps[((orow * 64 + p0 + 8) << 1) + half] = f2b((acc[s][1][r] + b1) * 0.25f);
            }
        }
    }

    // ---- K (keep accs), then V ----
    f32x4 acck[2][2];
    LOAD_B(wkm);
    RUN_MFMA(acck);
    LOAD_B(wvm);
    RUN_MFMA(acc);                         // acc now holds V

    {
        const float bk0 = bk[c0], bk1 = bk[c1];
        const float bv0 = bv[c0], bv1 = bv[c1];
        ushort* kvs = (ushort*)kv;
#pragma unroll
        for (int s = 0; s < 2; ++s) {
            if (rb + s * 16 >= N_NODES) break;
#pragma unroll
            for (int r = 0; r < 4; ++r) {
                const size_t orow = rb + s * 16 + quad * 4 + r;
                const size_t b0a = (orow * 64 + p0) << 2;
                const size_t b1a = (orow * 64 + p0 + 8) << 2;
                kvs[b0a + half]     = f2b(acck[s][0][r] + bk0);  // x pair
                kvs[b1a + half]     = f2b(acck[s][1][r] + bk1);
                kvs[b0a + 2 + half] = f2b(acc[s][0][r] + bv0);   // y pair
                kvs[b1a + 2 + half] = f2b(acc[s][1][r] + bv1);
            }
        }
    }
#undef LOAD_B
#undef RUN_MFMA
}

// ---------------------------------------------------------------------------
// One wave per destination node; predicated chunks of 8 edges -> uniform
// 8-deep load pipeline, no serial tail. Invalid lanes re-load edge-0's line
// (L1 hit) with ex forced to 0. No running max (scores ~ N(0,1)).
__global__ __launch_bounds__(256) void attn_fused(
    const uint* __restrict__ qp, const uint2* __restrict__ kv,
    const int* __restrict__ cnt, const ushort* __restrict__ slots,
    ushort* __restrict__ ao)
{
    const int lane = threadIdx.x & 63;
    const int node = blockIdx.x * 4 + (threadIdx.x >> 6);
    if (node >= N_NODES) return;

    const uint qraw = qp[(size_t)node * 64 + lane];
    const float q0 = __uint_as_float(qraw << 16);
    const float q1 = __uint_as_float(qraw & 0xffff0000u);

    int deg = cnt[node];
    if (deg > CAP) deg = CAP;
    const int myslot = (lane < deg) ? (int)slots[(size_t)node * CAP + lane] : 0;

    float ls[8] = {0,0,0,0,0,0,0,0};
    float Oa[8] = {0,0,0,0,0,0,0,0};
    float Ob[8] = {0,0,0,0,0,0,0,0};

    for (int base = 0; base < deg; base += 8) {
        int sj[8];
#pragma unroll
        for (int u = 0; u < 8; ++u) {
            int j  = base + u;
            int jj = (j < deg) ? j : 0;
            sj[u] = __shfl(myslot, jj);
        }
        uint2 rr[8];
#pragma unroll
        for (int u = 0; u < 8; ++u)
            rr[u] = kv[(size_t)sj[u] * 64 + lane];
#pragma unroll
        for (int u = 0; u < 8; ++u) {
            float k0 = __uint_as_float(rr[u].x << 16);
            float k1 = __uint_as_float(rr[u].x & 0xffff0000u);
            float p = q0 * k0 + q1 * k1;      // q pre-scaled by 1/sqrt(d)
            p += __shfl_xor(p, 8);
            p += __shfl_xor(p, 16);
            p += __shfl_xor(p, 32);
            float ex = (base + u < deg) ? __expf(fminf(p, 80.f)) : 0.f;
            ls[u] += ex;
            Oa[u] += ex * __uint_as_float(rr[u].y << 16);
            Ob[u] += ex * __uint_as_float(rr[u].y & 0xffff0000u);
        }
    }

    const float l  = ((ls[0] + ls[1]) + (ls[2] + ls[3])) + ((ls[4] + ls[5]) + (ls[6] + ls[7]));
    const float O0 = ((Oa[0] + Oa[1]) + (Oa[2] + Oa[3])) + ((Oa[4] + Oa[5]) + (Oa[6] + Oa[7]));
    const float O1 = ((Ob[0] + Ob[1]) + (Ob[2] + Ob[3])) + ((Ob[4] + Ob[5]) + (Ob[6] + Ob[7]));
    const float inv = (l > 0.f) ? 1.f / l : 0.f;   // deg-0 -> 0 (bo added later)

    const int ce = 16 * (lane >> 3) + (lane & 7);
    ao[(size_t)node * HID + ce]     = f2b(O0 * inv);
    ao[(size_t)node * HID + ce + 8] = f2b(O1 * inv);
}

// ---------------------------------------------------------------------------
// Output projection: C = A(bf16) @ Wo^T + bo, fp32 row-major. 64-row blocks;
// B-fragments register-resident, loaded once per wave.
__global__ __launch_bounds__(256) void gemm_out(
    const ushort* __restrict__ A, const ushort* __restrict__ W,
    const float* __restrict__ bias, float* __restrict__ out)
{
    const int lane = threadIdx.x & 63;
    const int wid  = threadIdx.x >> 6;
    const int mrow = lane & 15;
    const int quad = lane >> 4;
    const int rb   = blockIdx.x * 64;

    const int c0 = wid * 32 + mrow;
    const int c1 = c0 + 16;

    bf16x8 bfr[2][4];
#pragma unroll
    for (int kc = 0; kc < 4; ++kc) {
        bfr[0][kc] = *(const bf16x8*)(W + c0 * HID + kc * 32 + quad * 8);
        bfr[1][kc] = *(const bf16x8*)(W + c1 * HID + kc * 32 + quad * 8);
    }

    f32x4 acc[4][2];
#pragma unroll
    for (int s = 0; s < 4; ++s) {
        acc[s][0] = (f32x4){0.f, 0.f, 0.f, 0.f};
        acc[s][1] = (f32x4){0.f, 0.f, 0.f, 0.f};
    }

#pragma unroll
    for (int s = 0; s < 4; ++s) {
        if (rb + s * 16 >= N_NODES) break;
        const ushort* ap = A + (size_t)(rb + s * 16 + mrow) * HID + quad * 8;
        bf16x8 a0 = *(const bf16x8*)(ap);
        bf16x8 a1 = *(const bf16x8*)(ap + 32);
        bf16x8 a2 = *(const bf16x8*)(ap + 64);
        bf16x8 a3 = *(const bf16x8*)(ap + 96);
        acc[s][0] = __builtin_amdgcn_mfma_f32_16x16x32_bf16(a0, bfr[0][0], acc[s][0], 0, 0, 0);
        acc[s][1] = __builtin_amdgcn_mfma_f32_16x16x32_bf16(a0, bfr[1][0], acc[s][1], 0, 0, 0);
        acc[s][0] = __builtin_amdgcn_mfma_f32_16x16x32_bf16(a1, bfr[0][1], acc[s][0], 0, 0, 0);
        acc[s][1] = __builtin_amdgcn_mfma_f32_16x16x32_bf16(a1, bfr[1][1], acc[s][1], 0, 0, 0);
        acc[s][0] = __builtin_amdgcn_mfma_f32_16x16x32_bf16(a2, bfr[0][2], acc[s][0], 0, 0, 0);
        acc[s][1] = __builtin_amdgcn_mfma_f32_16x16x32_bf16(a2, bfr[1][2], acc[s][1], 0, 0, 0);
        acc[s][0] = __builtin_amdgcn_mfma_f32_16x16x32_bf16(a3, bfr[0][3], acc[s][0], 0, 0, 0);
        acc[s][1] = __builtin_amdgcn_mfma_f32_16x16x32_bf16(a3, bfr[1][3], acc[s][1], 0, 0, 0);
    }

#pragma unroll
    for (int t = 0; t < 2; ++t) {
        const int c = (t == 0) ? c0 : c1;
        const float bc = bias[c];
#pragma unroll
        for (int s = 0; s < 4; ++s) {
            if (rb + s * 16 >= N_NODES) break;
#pragma unroll
            for (int r = 0; r < 4; ++r) {
                const size_t orow = rb + s * 16 + quad * 4 + r;
                out[orow * HID + c] = acc[s][t][r] + bc;
            }
        }
    }
}

// ---------------------------------------------------------------------------
extern "C" void kernel_launch(void* const* d_in, const int* in_sizes, int n_in,
                              void* d_out, int out_size, void* d_ws, size_t ws_size,
                              hipStream_t stream)
{
    const float* h    = (const float*)d_in[0];
    const int*   rows = (const int*)  d_in[1];
    const int*   cols = (const int*)  d_in[2];
    const float* Wq   = (const float*)d_in[3];
    const float* bq   = (const float*)d_in[4];
    const float* Wk   = (const float*)d_in[5];
    const float* bk   = (const float*)d_in[6];
    const float* Wv   = (const float*)d_in[7];
    const float* bv   = (const float*)d_in[8];
    const float* Wo   = (const float*)d_in[9];
    const float* bo   = (const float*)d_in[10];
    float* out = (float*)d_out;

    char* ws = (char*)d_ws;
    uint*   qp    = (uint*)ws;    ws += (size_t)N_NODES * 64 * 4;   // 12.8 MB
    uint2*  kv    = (uint2*)ws;   ws += (size_t)N_NODES * 64 * 8;   // 25.6 MB
    ushort* aob   = (ushort*)ws;  ws += (size_t)N_NODES * HID * 2;  // 12.8 MB
    ushort* wqb   = (ushort*)ws;  ws += 128 * 128 * 2;
    ushort* wkb   = (ushort*)ws;  ws += 128 * 128 * 2;
    ushort* wvb   = (ushort*)ws;  ws += 128 * 128 * 2;
    ushort* wob   = (ushort*)ws;  ws += 128 * 128 * 2;
    int*    cnt   = (int*)ws;     ws += (size_t)N_NODES * 4;
    ushort* slots = (ushort*)ws;  // N*CAP ushorts, 6.4 MB

    hipMemsetAsync(cnt, 0, N_NODES * sizeof(int), stream);

    dim3 blk(256);
    prep<<<(N_EDGES + 255) / 256, blk, 0, stream>>>(
        Wq, Wk, Wv, Wo, wqb, wkb, wvb, wob, rows, cols, cnt, slots);

    gemm_qkv<<<GQ_GRID, blk, 0, stream>>>(
        h, wqb, wkb, wvb, bq, bk, bv, qp, kv);

    attn_fused<<<(N_NODES + 3) / 4, blk, 0, stream>>>(qp, kv, cnt, slots, aob);

    gemm_out<<<GO_GRID, blk, 0, stream>>>(aob, wob, bo, out);
}